// Round 23
// baseline (572.192 us; speedup 1.0000x reference)
//
#include <hip/hip_runtime.h>
#include <cstdint>

#define NN 50000
#define DD 128
#define EE 600000
#define NBK 49          // row buckets of 1024
#define BCAP 14336      // sort2 LDS edge capacity (mean 12288, sigma~110)

typedef __attribute__((ext_vector_type(8))) short bf16x8;
typedef __attribute__((ext_vector_type(4))) float f32x4;

__device__ __forceinline__ float sigmoid_f(float x) {
    return 1.0f / (1.0f + __expf(-x));
}
__device__ __forceinline__ float tanh_f(float x) {
    float e = __expf(-2.0f * fabsf(x));
    float t = (1.0f - e) / (1.0f + e);
    return copysignf(t, x);
}
__device__ __forceinline__ unsigned short bf16_rn(float v) {
    unsigned u = __float_as_uint(v);
    u = u + 0x7fffu + ((u >> 16) & 1u);
    return (unsigned short)(u >> 16);
}
__device__ __forceinline__ float bf16_tf(unsigned short h) {
    return __uint_as_float(((unsigned)h) << 16);
}

// ---- weight packing into MFMA B-panels ------------------------------------
__global__ __launch_bounds__(256) void pack_w_kernel(const float* __restrict__ wx,
                                                     const float* __restrict__ wh,
                                                     unsigned short* __restrict__ Wp) {
    int idx = blockIdx.x * 256 + threadIdx.x;   // 24*512*32
    if (idx >= 24 * 512 * 32) return;
    int k8 = idx & 31;
    int n = (idx >> 5) & 511;
    int kb = idx >> 14;
    int grp = kb >> 2;
    int k = (kb & 3) * 32 + k8;
    float v = 0.f;
    if (grp < 3) {
        if (n < 384) v = wx[n * 128 + k];
    } else {
        if (n < 256) v = wh[n * 128 + k];
        else if (n >= 384) v = wh[(n - 128) * 128 + k];
    }
    unsigned short hi = bf16_rn(v);
    bool lo = (grp == 2) || (grp == 5);
    Wp[idx] = lo ? bf16_rn(v - bf16_tf(hi)) : hi;
}

// ---- CSR build ------------------------------------------------------------

__global__ __launch_bounds__(256) void bhist_kernel(const int* __restrict__ rows,
                                                    int* __restrict__ bcnt4) {
    __shared__ int lc[NBK];
    const int tid = threadIdx.x;
    const int k = blockIdx.y;
    const int e0 = blockIdx.x * 2048;
    if (tid < NBK) lc[tid] = 0;
    __syncthreads();
    #pragma unroll
    for (int i = 0; i < 8; ++i) {
        int e = e0 + i * 256 + tid;
        if (e < EE) atomicAdd(&lc[rows[(size_t)k * EE + e] >> 10], 1);
    }
    __syncthreads();
    if (tid < NBK && lc[tid]) atomicAdd(&bcnt4[k * NBK + tid], lc[tid]);
}

__global__ __launch_bounds__(64) void bscan_kernel(const int* __restrict__ bcnt4,
                                                   int* __restrict__ bbase4,
                                                   int* __restrict__ bcur4) {
    int k = threadIdx.x;
    if (k < 4) {
        int run = 0;
        for (int b = 0; b < NBK; ++b) {
            bbase4[k * NBK + b] = run;
            bcur4[k * NBK + b] = run;
            run += bcnt4[k * NBK + b];
        }
    }
}

__global__ __launch_bounds__(256) void bscat_kernel(const int* __restrict__ rows,
                                                    const int* __restrict__ cols,
                                                    const float* __restrict__ vals,
                                                    int* __restrict__ bcur4,
                                                    int2* __restrict__ st2) {
    __shared__ int lcnt[4][NBK];
    __shared__ int sstart4[4][NBK];
    __shared__ int sstart_b[NBK];
    __shared__ int gbase[NBK];
    __shared__ int ltot;
    __shared__ int sw0[2048];
    __shared__ int sw1[2048];
    __shared__ unsigned char sbk[2048];

    const int tid = threadIdx.x;
    const int w = tid >> 6;
    const int k = blockIdx.y;
    const int e0 = blockIdx.x * 2048;

    if (tid < NBK) { lcnt[0][tid] = 0; lcnt[1][tid] = 0; lcnt[2][tid] = 0; lcnt[3][tid] = 0; }
    __syncthreads();

    int eb[8], er[8], ew0[8], ew1[8];
    #pragma unroll
    for (int i = 0; i < 8; ++i) {
        int e = e0 + i * 256 + tid;
        eb[i] = -1;
        if (e < EE) {
            size_t off = (size_t)k * EE + e;
            int r = rows[off];
            int b = r >> 10;
            eb[i] = b;
            er[i] = atomicAdd(&lcnt[w][b], 1);
            ew0[i] = ((r & 1023) << 17) | cols[off];
            ew1[i] = __float_as_int(vals[off]);
        }
    }
    __syncthreads();
    if (tid == 0) {
        int run = 0;
        for (int b = 0; b < NBK; ++b) {
            sstart_b[b] = run;
            #pragma unroll
            for (int q = 0; q < 4; ++q) { sstart4[q][b] = run; run += lcnt[q][b]; }
        }
        ltot = run;
    }
    __syncthreads();
    if (tid < NBK) {
        int n = (sstart4[3][tid] + lcnt[3][tid]) - sstart_b[tid];
        if (n) gbase[tid] = atomicAdd(&bcur4[k * NBK + tid], n);
    }
    __syncthreads();
    #pragma unroll
    for (int i = 0; i < 8; ++i) {
        if (eb[i] >= 0) {
            int slot = sstart4[w][eb[i]] + er[i];
            sw0[slot] = ew0[i];
            sw1[slot] = ew1[i];
            sbk[slot] = (unsigned char)eb[i];
        }
    }
    __syncthreads();
    const int tot = ltot;
    #pragma unroll
    for (int i = 0; i < 8; ++i) {
        int slot = i * 256 + tid;
        if (slot < tot) {
            int b = sbk[slot];
            int pos = gbase[b] + (slot - sstart_b[b]);
            st2[(size_t)k * EE + pos] = make_int2(sw0[slot], sw1[slot]);
        }
    }
}

__global__ __launch_bounds__(1024, 1) void sort2_kernel(const int2* __restrict__ st2,
                                                        const int* __restrict__ bbase4,
                                                        const int* __restrict__ bcnt4,
                                                        int* __restrict__ row_ptr4,
                                                        int2* __restrict__ epair4) {
    __shared__ int cnt[1024];
    __shared__ int cur[1024];
    __shared__ int2 obuf[BCAP];

    const int tid = threadIdx.x;
    const int b = blockIdx.x;
    const int k = blockIdx.y;
    const int base = bbase4[k * NBK + b];
    const int n = bcnt4[k * NBK + b];

    cnt[tid] = 0;
    __syncthreads();
    for (int i = tid; i < n; i += 1024)
        atomicAdd(&cnt[st2[(size_t)k * EE + base + i].x >> 17], 1);
    __syncthreads();

    int v = cnt[tid];
    cur[tid] = v;
    __syncthreads();
    for (int d = 1; d < 1024; d <<= 1) {
        int t = (tid >= d) ? cur[tid - d] : 0;
        __syncthreads();
        cur[tid] += t;
        __syncthreads();
    }
    int excl = cur[tid] - v;

    int grow = b * 1024 + tid;
    if (grow <= NN) row_ptr4[k * (NN + 1) + grow] = base + excl;

    cur[tid] = excl;
    __syncthreads();
    for (int i = tid; i < n; i += 1024) {
        int2 p = st2[(size_t)k * EE + base + i];
        int rl = p.x >> 17;
        int pos = atomicAdd(&cur[rl], 1);
        if (pos < BCAP) obuf[pos] = make_int2(p.x & 0x1FFFF, p.y);
    }
    __syncthreads();
    for (int i = tid; i < n; i += 1024)
        epair4[(size_t)k * EE + base + i] = obuf[i];
}

// ---- MEGA kernel: all 4 diffusion steps, h row-block-local in LDS ----------
// Block owns 64 rows for the WHOLE recurrence (GRU is row-local). Per step:
// fused SpMM -> slabs, phase A MFMA, stageH (hLds->slabs, LDS only), phase B
// MFMA, GRU epilogue -> hLds (packed split-bf16). Only the final step writes
// global (hout). No Hpk buffer: saves 154 MB HBM/call + 3 launches.
__global__ __launch_bounds__(512, 4)
void mega_kernel(const float* __restrict__ x,
                 const int* __restrict__ row_ptr4,
                 const int2* __restrict__ epair4,
                 float* __restrict__ hout,
                 const unsigned short* __restrict__ Wp,
                 const float* __restrict__ bx,
                 const float* __restrict__ bh) {
    __shared__ unsigned short sA[2 * 64 * 128];   // 32 KB (hi, lo slabs)
    __shared__ unsigned int hLds[64 * 128];       // 32 KB packed h state

    const int tid = threadIdx.x;
    const int row0 = blockIdx.x * 64;
    const int lane = tid & 63;
    const int w = tid >> 6;        // 0..7
    const int g = lane >> 4;       // 0..3
    const int m16 = lane & 15;

    // LDS->LDS: de-interleave packed h into hi/lo slabs
    auto stageH = [&]() {
        #pragma unroll
        for (int it = 0; it < 4; ++it) {
            int idx = it * 512 + tid;         // 0..2047
            int row = idx >> 5;               // 0..63
            int j0 = (idx & 31) * 4;
            uint4 v = *reinterpret_cast<const uint4*>(&hLds[row * 128 + j0]);
            ushort4 hh = make_ushort4(v.x & 0xFFFF, v.y & 0xFFFF, v.z & 0xFFFF, v.w & 0xFFFF);
            ushort4 hl = make_ushort4(v.x >> 16, v.y >> 16, v.z >> 16, v.w >> 16);
            int sw = (j0 >> 3) ^ (row & 7);
            int b0 = ((0 * 64 + row) * 16 + sw) * 8 + (j0 & 7);
            int b1 = ((1 * 64 + row) * 16 + sw) * 8 + (j0 & 7);
            *reinterpret_cast<ushort4*>(sA + b0) = hh;
            *reinterpret_cast<ushort4*>(sA + b1) = hl;
        }
    };

    f32x4 acc[4][4];               // [gate][mt]

    // one 12-MFMA cluster: B from panel kbW, A from slab arr at k-quad kq
    auto do_kb2 = [&](int kbW, int kq, int arr, int G0, int G1, int G2) {
        bf16x8 bfr[3];
        const int Gs[3] = {G0, G1, G2};
        #pragma unroll
        for (int i = 0; i < 3; ++i) {
            int n = Gs[i] * 128 + w * 16 + m16;
            bfr[i] = *reinterpret_cast<const bf16x8*>(
                Wp + ((size_t)(kbW * 512 + n)) * 32 + g * 8);
        }
        bf16x8 afr[4];
        #pragma unroll
        for (int mt = 0; mt < 4; ++mt) {
            int row = mt * 16 + m16;
            int sw = (kq * 4 + g) ^ (row & 7);
            afr[mt] = *reinterpret_cast<const bf16x8*>(
                sA + ((arr * 64 + row) * 16 + sw) * 8);
        }
        __builtin_amdgcn_s_setprio(1);
        #pragma unroll
        for (int mt = 0; mt < 4; ++mt) {
            acc[G0][mt] = __builtin_amdgcn_mfma_f32_16x16x32_bf16(afr[mt], bfr[0], acc[G0][mt], 0, 0, 0);
            acc[G1][mt] = __builtin_amdgcn_mfma_f32_16x16x32_bf16(afr[mt], bfr[1], acc[G1][mt], 0, 0, 0);
            acc[G2][mt] = __builtin_amdgcn_mfma_f32_16x16x32_bf16(afr[mt], bfr[2], acc[G2][mt], 0, 0, 0);
        }
        __builtin_amdgcn_s_setprio(0);
    };

    #pragma unroll
    for (int s = 0; s < 4; ++s) {
        const bool first = (s == 0);
        const bool last = (s == 3);
        const int kadj = 3 - s;   // adj_list reversed
        const int* __restrict__ rp = row_ptr4 + kadj * (NN + 1);
        const int2* __restrict__ ep = epair4 + (size_t)kadj * EE;

        if (s > 0) __syncthreads();   // prior phase-B/epilogue slab reads done

        // ---- fused SpMM: 16 half-waves x 4 passes; 32 lanes/row
        {
            const int hw = tid >> 5;
            const int l32 = tid & 31;
            const int d0 = l32 * 4;
            #pragma unroll
            for (int p = 0; p < 4; ++p) {
                int rl = p * 16 + hw;
                int grow = row0 + rl;
                float4 a0 = make_float4(0.f, 0.f, 0.f, 0.f);
                float4 a1 = a0, a2 = a0, a3 = a0;
                if (grow < NN) {
                    int start = rp[grow];
                    int end = rp[grow + 1];
                    int e = start;
                    for (; e + 3 < end; e += 4) {
                        int2 p0 = ep[e], p1 = ep[e + 1], p2 = ep[e + 2], p3 = ep[e + 3];
                        float4 x0 = *reinterpret_cast<const float4*>(x + (size_t)p0.x * DD + d0);
                        float4 x1 = *reinterpret_cast<const float4*>(x + (size_t)p1.x * DD + d0);
                        float4 x2 = *reinterpret_cast<const float4*>(x + (size_t)p2.x * DD + d0);
                        float4 x3 = *reinterpret_cast<const float4*>(x + (size_t)p3.x * DD + d0);
                        float v0 = __int_as_float(p0.y), v1 = __int_as_float(p1.y);
                        float v2 = __int_as_float(p2.y), v3 = __int_as_float(p3.y);
                        a0.x += v0 * x0.x; a0.y += v0 * x0.y; a0.z += v0 * x0.z; a0.w += v0 * x0.w;
                        a1.x += v1 * x1.x; a1.y += v1 * x1.y; a1.z += v1 * x1.z; a1.w += v1 * x1.w;
                        a2.x += v2 * x2.x; a2.y += v2 * x2.y; a2.z += v2 * x2.z; a2.w += v2 * x2.w;
                        a3.x += v3 * x3.x; a3.y += v3 * x3.y; a3.z += v3 * x3.z; a3.w += v3 * x3.w;
                    }
                    for (; e < end; ++e) {
                        int2 p0 = ep[e];
                        float v0 = __int_as_float(p0.y);
                        float4 x0 = *reinterpret_cast<const float4*>(x + (size_t)p0.x * DD + d0);
                        a0.x += v0 * x0.x; a0.y += v0 * x0.y; a0.z += v0 * x0.z; a0.w += v0 * x0.w;
                    }
                }
                float o[4];
                o[0] = fmaxf((a0.x + a1.x) + (a2.x + a3.x), 0.f);
                o[1] = fmaxf((a0.y + a1.y) + (a2.y + a3.y), 0.f);
                o[2] = fmaxf((a0.z + a1.z) + (a2.z + a3.z), 0.f);
                o[3] = fmaxf((a0.w + a1.w) + (a2.w + a3.w), 0.f);
                ushort4 vh, vl;
                unsigned short h0 = bf16_rn(o[0]); vh.x = h0; vl.x = bf16_rn(o[0] - bf16_tf(h0));
                unsigned short h1 = bf16_rn(o[1]); vh.y = h1; vl.y = bf16_rn(o[1] - bf16_tf(h1));
                unsigned short h2 = bf16_rn(o[2]); vh.z = h2; vl.z = bf16_rn(o[2] - bf16_tf(h2));
                unsigned short h3 = bf16_rn(o[3]); vh.w = h3; vl.w = bf16_rn(o[3] - bf16_tf(h3));
                int slot = l32 >> 1;
                int sw = slot ^ (rl & 7);
                int bi = ((0 * 64 + rl) * 16 + sw) * 8 + (d0 & 7);
                *reinterpret_cast<ushort4*>(sA + bi) = vh;
                *reinterpret_cast<ushort4*>(sA + (64 * 128) + bi) = vl;
            }
        }
        __syncthreads();

        #pragma unroll
        for (int G = 0; G < 4; ++G)
            #pragma unroll
            for (int mt = 0; mt < 4; ++mt)
                acc[G][mt] = (f32x4){0.f, 0.f, 0.f, 0.f};

        // phase A: x-side, kq-major; Whi panel reused (2nd use hits L1)
        for (int kq = 0; kq < 4; ++kq) {
            do_kb2(kq,     kq, 0, 0, 1, 2);   // Rh x Whi
            do_kb2(kq,     kq, 1, 0, 1, 2);   // Rl x Whi (L1 hit)
            do_kb2(8 + kq, kq, 0, 0, 1, 2);   // Rh x Wlo
        }

        // phase B: h-side (skip on first step: h0 = 0)
        if (!first) {
            __syncthreads();
            stageH();
            __syncthreads();
            for (int kq = 0; kq < 4; ++kq) {
                do_kb2(12 + kq, kq, 0, 0, 1, 3);   // Hh x Whi_h
                do_kb2(12 + kq, kq, 1, 0, 1, 3);   // Hl x Whi_h (L1 hit)
                do_kb2(20 + kq, kq, 0, 0, 1, 3);   // Hh x Wlo_h
            }
        }

        // ---- GRU epilogue: C layout col=m16, row=g*4+ii (m89)
        {
            int j = w * 16 + m16;
            float bxr = bx[j], bxi = bx[128 + j], bxn = bx[256 + j];
            float bhr = bh[j], bhi = bh[128 + j], bhn = bh[256 + j];
            #pragma unroll
            for (int mt = 0; mt < 4; ++mt) {
                #pragma unroll
                for (int ii = 0; ii < 4; ++ii) {
                    int lrow = mt * 16 + g * 4 + ii;
                    int grow = row0 + lrow;
                    if (grow >= NN) continue;
                    float rr = acc[0][mt][ii] + bxr + bhr;
                    float ri = acc[1][mt][ii] + bxi + bhi;
                    float rin = acc[2][mt][ii] + bxn;
                    float rhn = bhn;
                    float ho = 0.f;
                    if (!first) {
                        rhn += acc[3][mt][ii];
                        int sw = (j >> 3) ^ (lrow & 7);
                        int bi = (lrow * 16 + sw) * 8 + (j & 7);
                        ho = bf16_tf(sA[bi]) + bf16_tf(sA[64 * 128 + bi]);
                    }
                    float rg = sigmoid_f(rr);
                    float ig = sigmoid_f(ri);
                    float ng = tanh_f(rin + rg * rhn);
                    float hy = ng + ig * (ho - ng);
                    if (last) {
                        hout[(size_t)grow * 128 + j] = hy;
                    } else {
                        unsigned short hh = bf16_rn(hy);
                        unsigned short hl = bf16_rn(hy - bf16_tf(hh));
                        hLds[lrow * 128 + j] = (unsigned)hh | ((unsigned)hl << 16);
                    }
                }
            }
        }
    }
}

// LayerNorm
__global__ __launch_bounds__(256) void ln_kernel(float* __restrict__ h,
                                                 const float* __restrict__ g,
                                                 const float* __restrict__ b) {
    int tid = threadIdx.x;
    int lane = tid & 31;
    int rl = tid >> 5;
    int row = blockIdx.x * 8 + rl;
    if (row >= NN) return;
    float4 v = *reinterpret_cast<const float4*>(h + (size_t)row * DD + lane * 4);
    float s = v.x + v.y + v.z + v.w;
    #pragma unroll
    for (int m = 16; m >= 1; m >>= 1) s += __shfl_xor(s, m, 64);
    float mean = s * (1.0f / DD);
    float dx = v.x - mean, dy = v.y - mean, dz = v.z - mean, dw = v.w - mean;
    float q = dx * dx + dy * dy + dz * dz + dw * dw;
    #pragma unroll
    for (int m = 16; m >= 1; m >>= 1) q += __shfl_xor(q, m, 64);
    float var = q * (1.0f / DD);
    float inv = 1.0f / sqrtf(var + 1e-5f);
    float4 gv = *reinterpret_cast<const float4*>(g + lane * 4);
    float4 bv = *reinterpret_cast<const float4*>(b + lane * 4);
    float4 o;
    o.x = dx * inv * gv.x + bv.x;
    o.y = dy * inv * gv.y + bv.y;
    o.z = dz * inv * gv.z + bv.z;
    o.w = dw * inv * gv.w + bv.w;
    *reinterpret_cast<float4*>(h + (size_t)row * DD + lane * 4) = o;
}

static inline size_t align_up(size_t v, size_t a) { return (v + a - 1) & ~(a - 1); }

extern "C" void kernel_launch(void* const* d_in, const int* in_sizes, int n_in,
                              void* d_out, int out_size, void* d_ws, size_t ws_size,
                              hipStream_t stream) {
    const float* x    = (const float*)d_in[0];
    const float* vals = (const float*)d_in[1];
    const float* wx   = (const float*)d_in[2];
    const float* bx   = (const float*)d_in[3];
    const float* wh   = (const float*)d_in[4];
    const float* bh   = (const float*)d_in[5];
    const float* lng  = (const float*)d_in[6];
    const float* lnb  = (const float*)d_in[7];
    const int* rows   = (const int*)d_in[8];
    const int* cols   = (const int*)d_in[9];

    float* hout = (float*)d_out;

    size_t off = 0;
    char* wsb = (char*)d_ws;
    int2* st2 = (int2*)(wsb + off);     off = align_up(off + (size_t)4 * EE * 8, 256);
    unsigned short* Wp = (unsigned short*)(wsb + off); off = align_up(off + (size_t)24 * 512 * 32 * 2, 256);
    int* row_ptr4 = (int*)(wsb + off);  off = align_up(off + (size_t)4 * (NN + 1) * 4, 256);
    int2* epair4 = (int2*)(wsb + off);  off = align_up(off + (size_t)4 * EE * 8, 256);
    int* bcnt4 = (int*)(wsb + off);     off = align_up(off + (size_t)4 * NBK * 4, 256);
    int* bbase4 = (int*)(wsb + off);    off = align_up(off + (size_t)4 * NBK * 4, 256);
    int* bcur4 = (int*)(wsb + off);     off = align_up(off + (size_t)4 * NBK * 4, 256);

    (void)in_sizes; (void)n_in; (void)out_size; (void)ws_size;

    pack_w_kernel<<<1536, 256, 0, stream>>>(wx, wh, Wp);

    hipMemsetAsync(bcnt4, 0, (size_t)4 * NBK * sizeof(int), stream);
    dim3 e2grid((EE + 2047) / 2048, 4);          // 293 x 4
    bhist_kernel<<<e2grid, 256, 0, stream>>>(rows, bcnt4);
    bscan_kernel<<<1, 64, 0, stream>>>(bcnt4, bbase4, bcur4);
    bscat_kernel<<<e2grid, 256, 0, stream>>>(rows, cols, vals, bcur4, st2);
    dim3 sgrid(NBK, 4);                          // 49 x 4
    sort2_kernel<<<sgrid, 1024, 0, stream>>>(st2, bbase4, bcnt4, row_ptr4, epair4);

    const int mgrid = (NN + 63) / 64;            // 782
    mega_kernel<<<mgrid, 512, 0, stream>>>(x, row_ptr4, epair4, hout, Wp, bx, bh);

    ln_kernel<<<(NN + 7) / 8, 256, 0, stream>>>(hout, lng, lnb);
}

// Round 24
// 406.195 us; speedup vs baseline: 1.4087x; 1.4087x over previous
//
#include <hip/hip_runtime.h>
#include <cstdint>

#define NN 50000
#define DD 128
#define EE 600000
#define NBK 49          // row buckets of 1024
#define BCAP 14336      // sort2 LDS edge capacity (mean 12288, sigma~110)

typedef __attribute__((ext_vector_type(8))) short bf16x8;
typedef __attribute__((ext_vector_type(4))) float f32x4;

__device__ __forceinline__ float sigmoid_f(float x) {
    return 1.0f / (1.0f + __expf(-x));
}
__device__ __forceinline__ float tanh_f(float x) {
    float e = __expf(-2.0f * fabsf(x));
    float t = (1.0f - e) / (1.0f + e);
    return copysignf(t, x);
}
__device__ __forceinline__ unsigned short bf16_rn(float v) {
    unsigned u = __float_as_uint(v);
    u = u + 0x7fffu + ((u >> 16) & 1u);
    return (unsigned short)(u >> 16);
}
__device__ __forceinline__ float bf16_tf(unsigned short h) {
    return __uint_as_float(((unsigned)h) << 16);
}

// ---- weight packing into MFMA B-panels ------------------------------------
__global__ __launch_bounds__(256) void pack_w_kernel(const float* __restrict__ wx,
                                                     const float* __restrict__ wh,
                                                     unsigned short* __restrict__ Wp) {
    int idx = blockIdx.x * 256 + threadIdx.x;   // 24*512*32
    if (idx >= 24 * 512 * 32) return;
    int k8 = idx & 31;
    int n = (idx >> 5) & 511;
    int kb = idx >> 14;
    int grp = kb >> 2;
    int k = (kb & 3) * 32 + k8;
    float v = 0.f;
    if (grp < 3) {
        if (n < 384) v = wx[n * 128 + k];
    } else {
        if (n < 256) v = wh[n * 128 + k];
        else if (n >= 384) v = wh[(n - 128) * 128 + k];
    }
    unsigned short hi = bf16_rn(v);
    bool lo = (grp == 2) || (grp == 5);
    Wp[idx] = lo ? bf16_rn(v - bf16_tf(hi)) : hi;
}

// ---- CSR build ------------------------------------------------------------

__global__ __launch_bounds__(256) void bhist_kernel(const int* __restrict__ rows,
                                                    int* __restrict__ bcnt4) {
    __shared__ int lc[NBK];
    const int tid = threadIdx.x;
    const int k = blockIdx.y;
    const int e0 = blockIdx.x * 2048;
    if (tid < NBK) lc[tid] = 0;
    __syncthreads();
    #pragma unroll
    for (int i = 0; i < 8; ++i) {
        int e = e0 + i * 256 + tid;
        if (e < EE) atomicAdd(&lc[rows[(size_t)k * EE + e] >> 10], 1);
    }
    __syncthreads();
    if (tid < NBK && lc[tid]) atomicAdd(&bcnt4[k * NBK + tid], lc[tid]);
}

__global__ __launch_bounds__(64) void bscan_kernel(const int* __restrict__ bcnt4,
                                                   int* __restrict__ bbase4,
                                                   int* __restrict__ bcur4) {
    int k = threadIdx.x;
    if (k < 4) {
        int run = 0;
        for (int b = 0; b < NBK; ++b) {
            bbase4[k * NBK + b] = run;
            bcur4[k * NBK + b] = run;
            run += bcnt4[k * NBK + b];
        }
    }
}

__global__ __launch_bounds__(256) void bscat_kernel(const int* __restrict__ rows,
                                                    const int* __restrict__ cols,
                                                    const float* __restrict__ vals,
                                                    int* __restrict__ bcur4,
                                                    int2* __restrict__ st2) {
    __shared__ int lcnt[4][NBK];
    __shared__ int sstart4[4][NBK];
    __shared__ int sstart_b[NBK];
    __shared__ int gbase[NBK];
    __shared__ int ltot;
    __shared__ int sw0[2048];
    __shared__ int sw1[2048];
    __shared__ unsigned char sbk[2048];

    const int tid = threadIdx.x;
    const int w = tid >> 6;
    const int k = blockIdx.y;
    const int e0 = blockIdx.x * 2048;

    if (tid < NBK) { lcnt[0][tid] = 0; lcnt[1][tid] = 0; lcnt[2][tid] = 0; lcnt[3][tid] = 0; }
    __syncthreads();

    int eb[8], er[8], ew0[8], ew1[8];
    #pragma unroll
    for (int i = 0; i < 8; ++i) {
        int e = e0 + i * 256 + tid;
        eb[i] = -1;
        if (e < EE) {
            size_t off = (size_t)k * EE + e;
            int r = rows[off];
            int b = r >> 10;
            eb[i] = b;
            er[i] = atomicAdd(&lcnt[w][b], 1);
            ew0[i] = ((r & 1023) << 17) | cols[off];
            ew1[i] = __float_as_int(vals[off]);
        }
    }
    __syncthreads();
    if (tid == 0) {
        int run = 0;
        for (int b = 0; b < NBK; ++b) {
            sstart_b[b] = run;
            #pragma unroll
            for (int q = 0; q < 4; ++q) { sstart4[q][b] = run; run += lcnt[q][b]; }
        }
        ltot = run;
    }
    __syncthreads();
    if (tid < NBK) {
        int n = (sstart4[3][tid] + lcnt[3][tid]) - sstart_b[tid];
        if (n) gbase[tid] = atomicAdd(&bcur4[k * NBK + tid], n);
    }
    __syncthreads();
    #pragma unroll
    for (int i = 0; i < 8; ++i) {
        if (eb[i] >= 0) {
            int slot = sstart4[w][eb[i]] + er[i];
            sw0[slot] = ew0[i];
            sw1[slot] = ew1[i];
            sbk[slot] = (unsigned char)eb[i];
        }
    }
    __syncthreads();
    const int tot = ltot;
    #pragma unroll
    for (int i = 0; i < 8; ++i) {
        int slot = i * 256 + tid;
        if (slot < tot) {
            int b = sbk[slot];
            int pos = gbase[b] + (slot - sstart_b[b]);
            st2[(size_t)k * EE + pos] = make_int2(sw0[slot], sw1[slot]);
        }
    }
}

__global__ __launch_bounds__(1024, 1) void sort2_kernel(const int2* __restrict__ st2,
                                                        const int* __restrict__ bbase4,
                                                        const int* __restrict__ bcnt4,
                                                        int* __restrict__ row_ptr4,
                                                        int2* __restrict__ epair4) {
    __shared__ int cnt[1024];
    __shared__ int cur[1024];
    __shared__ int2 obuf[BCAP];

    const int tid = threadIdx.x;
    const int b = blockIdx.x;
    const int k = blockIdx.y;
    const int base = bbase4[k * NBK + b];
    const int n = bcnt4[k * NBK + b];

    cnt[tid] = 0;
    __syncthreads();
    for (int i = tid; i < n; i += 1024)
        atomicAdd(&cnt[st2[(size_t)k * EE + base + i].x >> 17], 1);
    __syncthreads();

    int v = cnt[tid];
    cur[tid] = v;
    __syncthreads();
    for (int d = 1; d < 1024; d <<= 1) {
        int t = (tid >= d) ? cur[tid - d] : 0;
        __syncthreads();
        cur[tid] += t;
        __syncthreads();
    }
    int excl = cur[tid] - v;

    int grow = b * 1024 + tid;
    if (grow <= NN) row_ptr4[k * (NN + 1) + grow] = base + excl;

    cur[tid] = excl;
    __syncthreads();
    for (int i = tid; i < n; i += 1024) {
        int2 p = st2[(size_t)k * EE + base + i];
        int rl = p.x >> 17;
        int pos = atomicAdd(&cur[rl], 1);
        if (pos < BCAP) obuf[pos] = make_int2(p.x & 0x1FFFF, p.y);
    }
    __syncthreads();
    for (int i = tid; i < n; i += 1024)
        epair4[(size_t)k * EE + base + i] = obuf[i];
}

// ---- FUSED-STEP kernel: role-split blocks ----------------------------------
// gemm role (782 blocks): R21 MFMA split-bf16 dual-GEMM + GRU for step s-1.
// gather role (3125 blocks): SpMM relu(A.x) -> split-bf16 Rh/Rl for step s.
// Independent (double-buffered R); interleaved 1:4 so each CU co-hosts one
// memory-bound gather block with one MFMA gemm block (T5 setprio regime).
template <bool FIRST, bool LAST>
__global__ __launch_bounds__(512, 4)
void fused_step_kernel(const float* __restrict__ x,
                       const int* __restrict__ rp_g,
                       const int2* __restrict__ ep_g,
                       unsigned short* __restrict__ RhW,
                       unsigned short* __restrict__ RlW,
                       const unsigned short* __restrict__ RhR,
                       const unsigned short* __restrict__ RlR,
                       unsigned int* __restrict__ Hpk,
                       float* __restrict__ hout,
                       const unsigned short* __restrict__ Wp,
                       const float* __restrict__ bx,
                       const float* __restrict__ bh,
                       int gemm_cnt, int gather_cnt) {
    __shared__ unsigned short sA[2 * 64 * 128];   // 32 KB (gemm role only)

    const int bid = blockIdx.x;
    const int tid = threadIdx.x;

    bool is_gemm;
    int idx;
    if (gather_cnt == 0) { is_gemm = true;  idx = bid; }
    else if (gemm_cnt == 0) { is_gemm = false; idx = bid; }
    else if (bid % 5 == 0) { is_gemm = true;  idx = bid / 5; }
    else { is_gemm = false; idx = bid - bid / 5 - 1; }

    if (!is_gemm) {
        // ---- gather role: 16 rows/block, half-wave per row, 4-edge ILP
        const int hw = tid >> 5;       // 0..15
        const int l32 = tid & 31;
        const int d0 = l32 * 4;
        const int row = idx * 16 + hw;
        if (row >= NN) return;
        const int start = rp_g[row];
        const int end = rp_g[row + 1];
        float4 a0 = make_float4(0.f, 0.f, 0.f, 0.f);
        float4 a1 = a0, a2 = a0, a3 = a0;
        int e = start;
        for (; e + 3 < end; e += 4) {
            int2 p0 = ep_g[e], p1 = ep_g[e + 1], p2 = ep_g[e + 2], p3 = ep_g[e + 3];
            float4 x0 = *reinterpret_cast<const float4*>(x + (size_t)p0.x * DD + d0);
            float4 x1 = *reinterpret_cast<const float4*>(x + (size_t)p1.x * DD + d0);
            float4 x2 = *reinterpret_cast<const float4*>(x + (size_t)p2.x * DD + d0);
            float4 x3 = *reinterpret_cast<const float4*>(x + (size_t)p3.x * DD + d0);
            float v0 = __int_as_float(p0.y), v1 = __int_as_float(p1.y);
            float v2 = __int_as_float(p2.y), v3 = __int_as_float(p3.y);
            a0.x += v0 * x0.x; a0.y += v0 * x0.y; a0.z += v0 * x0.z; a0.w += v0 * x0.w;
            a1.x += v1 * x1.x; a1.y += v1 * x1.y; a1.z += v1 * x1.z; a1.w += v1 * x1.w;
            a2.x += v2 * x2.x; a2.y += v2 * x2.y; a2.z += v2 * x2.z; a2.w += v2 * x2.w;
            a3.x += v3 * x3.x; a3.y += v3 * x3.y; a3.z += v3 * x3.z; a3.w += v3 * x3.w;
        }
        for (; e < end; ++e) {
            int2 p0 = ep_g[e];
            float v0 = __int_as_float(p0.y);
            float4 x0 = *reinterpret_cast<const float4*>(x + (size_t)p0.x * DD + d0);
            a0.x += v0 * x0.x; a0.y += v0 * x0.y; a0.z += v0 * x0.z; a0.w += v0 * x0.w;
        }
        float o[4];
        o[0] = fmaxf((a0.x + a1.x) + (a2.x + a3.x), 0.f);
        o[1] = fmaxf((a0.y + a1.y) + (a2.y + a3.y), 0.f);
        o[2] = fmaxf((a0.z + a1.z) + (a2.z + a3.z), 0.f);
        o[3] = fmaxf((a0.w + a1.w) + (a2.w + a3.w), 0.f);
        ushort4 vh, vl;
        unsigned short h0 = bf16_rn(o[0]); vh.x = h0; vl.x = bf16_rn(o[0] - bf16_tf(h0));
        unsigned short h1 = bf16_rn(o[1]); vh.y = h1; vl.y = bf16_rn(o[1] - bf16_tf(h1));
        unsigned short h2 = bf16_rn(o[2]); vh.z = h2; vl.z = bf16_rn(o[2] - bf16_tf(h2));
        unsigned short h3 = bf16_rn(o[3]); vh.w = h3; vl.w = bf16_rn(o[3] - bf16_tf(h3));
        *reinterpret_cast<ushort4*>(RhW + (size_t)row * DD + d0) = vh;
        *reinterpret_cast<ushort4*>(RlW + (size_t)row * DD + d0) = vl;
        return;
    }

    // ---- gemm role (R21 body): 64 rows, 8 waves x 16 j, 3 live gates
    const int row0 = idx * 64;
    const int lane = tid & 63;
    const int w = tid >> 6;
    const int g = lane >> 4;
    const int m16 = lane & 15;

    f32x4 acc[4][4];
    #pragma unroll
    for (int G = 0; G < 4; ++G)
        #pragma unroll
        for (int mt = 0; mt < 4; ++mt)
            acc[G][mt] = (f32x4){0.f, 0.f, 0.f, 0.f};

    // stage A: Rh/Rl slabs, swizzled slot ^= row&7
    {
        #pragma unroll
        for (int it = 0; it < 4; ++it) {
            int arr = it >> 1;
            int idx2 = (it & 1) * 512 + tid;
            int row = idx2 >> 4;
            int slot = idx2 & 15;
            int grow = row0 + row;
            uint4 v = make_uint4(0, 0, 0, 0);
            if (grow < NN) {
                const unsigned short* src = arr ? RlR : RhR;
                v = *reinterpret_cast<const uint4*>(src + (size_t)grow * 128 + slot * 8);
            }
            int sw = slot ^ (row & 7);
            *reinterpret_cast<uint4*>(sA + ((arr * 64 + row) * 16 + sw) * 8) = v;
        }
    }
    __syncthreads();

    auto stageH = [&]() {
        #pragma unroll
        for (int it = 0; it < 4; ++it) {
            int idx2 = it * 512 + tid;
            int row = idx2 >> 5;
            int j0 = (idx2 & 31) * 4;
            int grow = row0 + row;
            uint4 v = make_uint4(0, 0, 0, 0);
            if (grow < NN)
                v = *reinterpret_cast<const uint4*>(Hpk + (size_t)grow * 128 + j0);
            ushort4 hh = make_ushort4(v.x & 0xFFFF, v.y & 0xFFFF, v.z & 0xFFFF, v.w & 0xFFFF);
            ushort4 hl = make_ushort4(v.x >> 16, v.y >> 16, v.z >> 16, v.w >> 16);
            int sw = (j0 >> 3) ^ (row & 7);
            int b0 = ((0 * 64 + row) * 16 + sw) * 8 + (j0 & 7);
            int b1 = ((1 * 64 + row) * 16 + sw) * 8 + (j0 & 7);
            *reinterpret_cast<ushort4*>(sA + b0) = hh;
            *reinterpret_cast<ushort4*>(sA + b1) = hl;
        }
    };

    auto do_kb2 = [&](int kbW, int kq, int arr, int G0, int G1, int G2) {
        bf16x8 bfr[3];
        const int Gs[3] = {G0, G1, G2};
        #pragma unroll
        for (int i = 0; i < 3; ++i) {
            int n = Gs[i] * 128 + w * 16 + m16;
            bfr[i] = *reinterpret_cast<const bf16x8*>(
                Wp + ((size_t)(kbW * 512 + n)) * 32 + g * 8);
        }
        bf16x8 afr[4];
        #pragma unroll
        for (int mt = 0; mt < 4; ++mt) {
            int row = mt * 16 + m16;
            int sw = (kq * 4 + g) ^ (row & 7);
            afr[mt] = *reinterpret_cast<const bf16x8*>(
                sA + ((arr * 64 + row) * 16 + sw) * 8);
        }
        __builtin_amdgcn_s_setprio(1);
        #pragma unroll
        for (int mt = 0; mt < 4; ++mt) {
            acc[G0][mt] = __builtin_amdgcn_mfma_f32_16x16x32_bf16(afr[mt], bfr[0], acc[G0][mt], 0, 0, 0);
            acc[G1][mt] = __builtin_amdgcn_mfma_f32_16x16x32_bf16(afr[mt], bfr[1], acc[G1][mt], 0, 0, 0);
            acc[G2][mt] = __builtin_amdgcn_mfma_f32_16x16x32_bf16(afr[mt], bfr[2], acc[G2][mt], 0, 0, 0);
        }
        __builtin_amdgcn_s_setprio(0);
    };

    // phase A: x-side, kq-major; Whi panel reused (2nd use hits L1)
    for (int kq = 0; kq < 4; ++kq) {
        do_kb2(kq,     kq, 0, 0, 1, 2);   // Rh x Whi
        do_kb2(kq,     kq, 1, 0, 1, 2);   // Rl x Whi (L1 hit)
        do_kb2(8 + kq, kq, 0, 0, 1, 2);   // Rh x Wlo
    }

    // phase B: h-side
    if (!FIRST) {
        __syncthreads();
        stageH();
        __syncthreads();
        for (int kq = 0; kq < 4; ++kq) {
            do_kb2(12 + kq, kq, 0, 0, 1, 3);   // Hh x Whi_h
            do_kb2(12 + kq, kq, 1, 0, 1, 3);   // Hl x Whi_h (L1 hit)
            do_kb2(20 + kq, kq, 0, 0, 1, 3);   // Hh x Wlo_h
        }
    }

    // GRU epilogue: C layout col=m16, row=g*4+ii (m89)
    {
        int j = w * 16 + m16;
        float bxr = bx[j], bxi = bx[128 + j], bxn = bx[256 + j];
        float bhr = bh[j], bhi = bh[128 + j], bhn = bh[256 + j];
        #pragma unroll
        for (int mt = 0; mt < 4; ++mt) {
            #pragma unroll
            for (int ii = 0; ii < 4; ++ii) {
                int lrow = mt * 16 + g * 4 + ii;
                int grow = row0 + lrow;
                if (grow >= NN) continue;
                float rr = acc[0][mt][ii] + bxr + bhr;
                float ri = acc[1][mt][ii] + bxi + bhi;
                float rin = acc[2][mt][ii] + bxn;
                float rhn = bhn;
                float ho = 0.f;
                if (!FIRST) {
                    rhn += acc[3][mt][ii];
                    int sw = (j >> 3) ^ (lrow & 7);
                    int bi = (lrow * 16 + sw) * 8 + (j & 7);
                    ho = bf16_tf(sA[bi]) + bf16_tf(sA[64 * 128 + bi]);
                }
                float rg = sigmoid_f(rr);
                float ig = sigmoid_f(ri);
                float ng = tanh_f(rin + rg * rhn);
                float hy = ng + ig * (ho - ng);
                if (LAST) {
                    hout[(size_t)grow * 128 + j] = hy;
                } else {
                    unsigned short hh = bf16_rn(hy);
                    unsigned short hl = bf16_rn(hy - bf16_tf(hh));
                    Hpk[(size_t)grow * 128 + j] = (unsigned)hh | ((unsigned)hl << 16);
                }
            }
        }
    }
}

// LayerNorm
__global__ __launch_bounds__(256) void ln_kernel(float* __restrict__ h,
                                                 const float* __restrict__ g,
                                                 const float* __restrict__ b) {
    int tid = threadIdx.x;
    int lane = tid & 31;
    int rl = tid >> 5;
    int row = blockIdx.x * 8 + rl;
    if (row >= NN) return;
    float4 v = *reinterpret_cast<const float4*>(h + (size_t)row * DD + lane * 4);
    float s = v.x + v.y + v.z + v.w;
    #pragma unroll
    for (int m = 16; m >= 1; m >>= 1) s += __shfl_xor(s, m, 64);
    float mean = s * (1.0f / DD);
    float dx = v.x - mean, dy = v.y - mean, dz = v.z - mean, dw = v.w - mean;
    float q = dx * dx + dy * dy + dz * dz + dw * dw;
    #pragma unroll
    for (int m = 16; m >= 1; m >>= 1) q += __shfl_xor(q, m, 64);
    float var = q * (1.0f / DD);
    float inv = 1.0f / sqrtf(var + 1e-5f);
    float4 gv = *reinterpret_cast<const float4*>(g + lane * 4);
    float4 bv = *reinterpret_cast<const float4*>(b + lane * 4);
    float4 o;
    o.x = dx * inv * gv.x + bv.x;
    o.y = dy * inv * gv.y + bv.y;
    o.z = dz * inv * gv.z + bv.z;
    o.w = dw * inv * gv.w + bv.w;
    *reinterpret_cast<float4*>(h + (size_t)row * DD + lane * 4) = o;
}

static inline size_t align_up(size_t v, size_t a) { return (v + a - 1) & ~(a - 1); }

extern "C" void kernel_launch(void* const* d_in, const int* in_sizes, int n_in,
                              void* d_out, int out_size, void* d_ws, size_t ws_size,
                              hipStream_t stream) {
    const float* x    = (const float*)d_in[0];
    const float* vals = (const float*)d_in[1];
    const float* wx   = (const float*)d_in[2];
    const float* bx   = (const float*)d_in[3];
    const float* wh   = (const float*)d_in[4];
    const float* bh   = (const float*)d_in[5];
    const float* lng  = (const float*)d_in[6];
    const float* lnb  = (const float*)d_in[7];
    const int* rows   = (const int*)d_in[8];
    const int* cols   = (const int*)d_in[9];

    float* hout = (float*)d_out;

    size_t off = 0;
    char* wsb = (char*)d_ws;
    unsigned short* Rh0 = (unsigned short*)(wsb + off); off = align_up(off + (size_t)NN * DD * 2, 256);
    unsigned short* Rl0 = (unsigned short*)(wsb + off); off = align_up(off + (size_t)NN * DD * 2, 256);
    unsigned short* Rh1 = (unsigned short*)(wsb + off); off = align_up(off + (size_t)NN * DD * 2, 256);
    unsigned short* Rl1 = (unsigned short*)(wsb + off); off = align_up(off + (size_t)NN * DD * 2, 256);
    unsigned int* Hpk = (unsigned int*)(wsb + off);    off = align_up(off + (size_t)NN * DD * 4, 256);
    unsigned short* Wp = (unsigned short*)(wsb + off); off = align_up(off + (size_t)24 * 512 * 32 * 2, 256);
    int* row_ptr4 = (int*)(wsb + off);  off = align_up(off + (size_t)4 * (NN + 1) * 4, 256);
    int2* epair4 = (int2*)(wsb + off);  off = align_up(off + (size_t)4 * EE * 8, 256);
    int* bcnt4 = (int*)(wsb + off);     off = align_up(off + (size_t)4 * NBK * 4, 256);
    int* bbase4 = (int*)(wsb + off);    off = align_up(off + (size_t)4 * NBK * 4, 256);
    int* bcur4 = (int*)(wsb + off);     off = align_up(off + (size_t)4 * NBK * 4, 256);
    // st2 (19.2 MB) aliases Rh1/Rl1 (25.6 MB): CSR build completes before
    // gather_1 first writes Rh1/Rl1 (stream-ordered)
    int2* st2 = (int2*)Rh1;

    (void)in_sizes; (void)n_in; (void)out_size; (void)ws_size;

    pack_w_kernel<<<1536, 256, 0, stream>>>(wx, wh, Wp);

    hipMemsetAsync(bcnt4, 0, (size_t)4 * NBK * sizeof(int), stream);
    dim3 e2grid((EE + 2047) / 2048, 4);          // 293 x 4
    bhist_kernel<<<e2grid, 256, 0, stream>>>(rows, bcnt4);
    bscan_kernel<<<1, 64, 0, stream>>>(bcnt4, bbase4, bcur4);
    bscat_kernel<<<e2grid, 256, 0, stream>>>(rows, cols, vals, bcur4, st2);
    dim3 sgrid(NBK, 4);                          // 49 x 4
    sort2_kernel<<<sgrid, 1024, 0, stream>>>(st2, bbase4, bcnt4, row_ptr4, epair4);

    const int GEMM_N = (NN + 63) / 64;           // 782
    const int GATH_N = NN / 16;                  // 3125
    const int MIX_N = GEMM_N * 5;                // 3910 >= 782+3125=3907, use 3907
    const int COMB_N = 3907;

    const int* rp3 = row_ptr4 + 3 * (NN + 1);
    const int* rp2 = row_ptr4 + 2 * (NN + 1);
    const int* rp1 = row_ptr4 + 1 * (NN + 1);
    const int* rp0 = row_ptr4 + 0 * (NN + 1);
    const int2* ep3 = epair4 + (size_t)3 * EE;
    const int2* ep2 = epair4 + (size_t)2 * EE;
    const int2* ep1 = epair4 + (size_t)1 * EE;
    const int2* ep0 = epair4 + (size_t)0 * EE;
    (void)MIX_N;

    // D0: gather_0 (step0, adj k=3) -> Rh0/Rl0
    fused_step_kernel<true, false><<<GATH_N, 512, 0, stream>>>(
        x, rp3, ep3, Rh0, Rl0, Rh0, Rl0, Hpk, hout, Wp, bx, bh, 0, GATH_N);
    // D1: gemm_0 (FIRST, reads Rh0) + gather_1 (adj k=2 -> Rh1)
    fused_step_kernel<true, false><<<COMB_N, 512, 0, stream>>>(
        x, rp2, ep2, Rh1, Rl1, Rh0, Rl0, Hpk, hout, Wp, bx, bh, GEMM_N, GATH_N);
    // D2: gemm_1 (reads Rh1) + gather_2 (adj k=1 -> Rh0)
    fused_step_kernel<false, false><<<COMB_N, 512, 0, stream>>>(
        x, rp1, ep1, Rh0, Rl0, Rh1, Rl1, Hpk, hout, Wp, bx, bh, GEMM_N, GATH_N);
    // D3: gemm_2 (reads Rh0) + gather_3 (adj k=0 -> Rh1)
    fused_step_kernel<false, false><<<COMB_N, 512, 0, stream>>>(
        x, rp0, ep0, Rh1, Rl1, Rh0, Rl0, Hpk, hout, Wp, bx, bh, GEMM_N, GATH_N);
    // D4: gemm_3 (LAST, reads Rh1) -> hout
    fused_step_kernel<false, true><<<GEMM_N, 512, 0, stream>>>(
        x, rp0, ep0, Rh0, Rl0, Rh1, Rl1, Hpk, hout, Wp, bx, bh, GEMM_N, 0);

    ln_kernel<<<(NN + 7) / 8, 256, 0, stream>>>(hout, lng, lnb);
}

// Round 25
// 401.457 us; speedup vs baseline: 1.4253x; 1.0118x over previous
//
#include <hip/hip_runtime.h>
#include <cstdint>

#define NN 50000
#define DD 128
#define EE 600000
#define NBK 49          // row buckets of 1024
#define BCAP 14336      // sort2 LDS edge capacity (mean 12288, sigma~110)

typedef __attribute__((ext_vector_type(8))) short bf16x8;
typedef __attribute__((ext_vector_type(4))) float f32x4;

__device__ __forceinline__ float sigmoid_f(float x) {
    return 1.0f / (1.0f + __expf(-x));
}
__device__ __forceinline__ float tanh_f(float x) {
    float e = __expf(-2.0f * fabsf(x));
    float t = (1.0f - e) / (1.0f + e);
    return copysignf(t, x);
}
__device__ __forceinline__ unsigned short bf16_rn(float v) {
    unsigned u = __float_as_uint(v);
    u = u + 0x7fffu + ((u >> 16) & 1u);
    return (unsigned short)(u >> 16);
}
__device__ __forceinline__ float bf16_tf(unsigned short h) {
    return __uint_as_float(((unsigned)h) << 16);
}

// ---- weight packing into MFMA B-panels ------------------------------------
__global__ __launch_bounds__(256) void pack_w_kernel(const float* __restrict__ wx,
                                                     const float* __restrict__ wh,
                                                     unsigned short* __restrict__ Wp) {
    int idx = blockIdx.x * 256 + threadIdx.x;   // 24*512*32
    if (idx >= 24 * 512 * 32) return;
    int k8 = idx & 31;
    int n = (idx >> 5) & 511;
    int kb = idx >> 14;
    int grp = kb >> 2;
    int k = (kb & 3) * 32 + k8;
    float v = 0.f;
    if (grp < 3) {
        if (n < 384) v = wx[n * 128 + k];
    } else {
        if (n < 256) v = wh[n * 128 + k];
        else if (n >= 384) v = wh[(n - 128) * 128 + k];
    }
    unsigned short hi = bf16_rn(v);
    bool lo = (grp == 2) || (grp == 5);
    Wp[idx] = lo ? bf16_rn(v - bf16_tf(hi)) : hi;
}

// ---- CSR build ------------------------------------------------------------

__global__ __launch_bounds__(256) void bhist_kernel(const int* __restrict__ rows,
                                                    int* __restrict__ bcnt4) {
    __shared__ int lc[NBK];
    const int tid = threadIdx.x;
    const int k = blockIdx.y;
    const int e0 = blockIdx.x * 2048;
    if (tid < NBK) lc[tid] = 0;
    __syncthreads();
    #pragma unroll
    for (int i = 0; i < 8; ++i) {
        int e = e0 + i * 256 + tid;
        if (e < EE) atomicAdd(&lc[rows[(size_t)k * EE + e] >> 10], 1);
    }
    __syncthreads();
    if (tid < NBK && lc[tid]) atomicAdd(&bcnt4[k * NBK + tid], lc[tid]);
}

__global__ __launch_bounds__(64) void bscan_kernel(const int* __restrict__ bcnt4,
                                                   int* __restrict__ bbase4,
                                                   int* __restrict__ bcur4) {
    int k = threadIdx.x;
    if (k < 4) {
        int run = 0;
        for (int b = 0; b < NBK; ++b) {
            bbase4[k * NBK + b] = run;
            bcur4[k * NBK + b] = run;
            run += bcnt4[k * NBK + b];
        }
    }
}

__global__ __launch_bounds__(256) void bscat_kernel(const int* __restrict__ rows,
                                                    const int* __restrict__ cols,
                                                    const float* __restrict__ vals,
                                                    int* __restrict__ bcur4,
                                                    int2* __restrict__ st2) {
    __shared__ int lcnt[4][NBK];
    __shared__ int sstart4[4][NBK];
    __shared__ int sstart_b[NBK];
    __shared__ int gbase[NBK];
    __shared__ int ltot;
    __shared__ int sw0[2048];
    __shared__ int sw1[2048];
    __shared__ unsigned char sbk[2048];

    const int tid = threadIdx.x;
    const int w = tid >> 6;
    const int k = blockIdx.y;
    const int e0 = blockIdx.x * 2048;

    if (tid < NBK) { lcnt[0][tid] = 0; lcnt[1][tid] = 0; lcnt[2][tid] = 0; lcnt[3][tid] = 0; }
    __syncthreads();

    int eb[8], er[8], ew0[8], ew1[8];
    #pragma unroll
    for (int i = 0; i < 8; ++i) {
        int e = e0 + i * 256 + tid;
        eb[i] = -1;
        if (e < EE) {
            size_t off = (size_t)k * EE + e;
            int r = rows[off];
            int b = r >> 10;
            eb[i] = b;
            er[i] = atomicAdd(&lcnt[w][b], 1);
            ew0[i] = ((r & 1023) << 17) | cols[off];
            ew1[i] = __float_as_int(vals[off]);
        }
    }
    __syncthreads();
    if (tid == 0) {
        int run = 0;
        for (int b = 0; b < NBK; ++b) {
            sstart_b[b] = run;
            #pragma unroll
            for (int q = 0; q < 4; ++q) { sstart4[q][b] = run; run += lcnt[q][b]; }
        }
        ltot = run;
    }
    __syncthreads();
    if (tid < NBK) {
        int n = (sstart4[3][tid] + lcnt[3][tid]) - sstart_b[tid];
        if (n) gbase[tid] = atomicAdd(&bcur4[k * NBK + tid], n);
    }
    __syncthreads();
    #pragma unroll
    for (int i = 0; i < 8; ++i) {
        if (eb[i] >= 0) {
            int slot = sstart4[w][eb[i]] + er[i];
            sw0[slot] = ew0[i];
            sw1[slot] = ew1[i];
            sbk[slot] = (unsigned char)eb[i];
        }
    }
    __syncthreads();
    const int tot = ltot;
    #pragma unroll
    for (int i = 0; i < 8; ++i) {
        int slot = i * 256 + tid;
        if (slot < tot) {
            int b = sbk[slot];
            int pos = gbase[b] + (slot - sstart_b[b]);
            st2[(size_t)k * EE + pos] = make_int2(sw0[slot], sw1[slot]);
        }
    }
}

__global__ __launch_bounds__(1024, 1) void sort2_kernel(const int2* __restrict__ st2,
                                                        const int* __restrict__ bbase4,
                                                        const int* __restrict__ bcnt4,
                                                        int* __restrict__ row_ptr4,
                                                        int2* __restrict__ epair4) {
    __shared__ int cnt[1024];
    __shared__ int cur[1024];
    __shared__ int2 obuf[BCAP];

    const int tid = threadIdx.x;
    const int b = blockIdx.x;
    const int k = blockIdx.y;
    const int base = bbase4[k * NBK + b];
    const int n = bcnt4[k * NBK + b];

    cnt[tid] = 0;
    __syncthreads();
    for (int i = tid; i < n; i += 1024)
        atomicAdd(&cnt[st2[(size_t)k * EE + base + i].x >> 17], 1);
    __syncthreads();

    int v = cnt[tid];
    cur[tid] = v;
    __syncthreads();
    for (int d = 1; d < 1024; d <<= 1) {
        int t = (tid >= d) ? cur[tid - d] : 0;
        __syncthreads();
        cur[tid] += t;
        __syncthreads();
    }
    int excl = cur[tid] - v;

    int grow = b * 1024 + tid;
    if (grow <= NN) row_ptr4[k * (NN + 1) + grow] = base + excl;

    cur[tid] = excl;
    __syncthreads();
    for (int i = tid; i < n; i += 1024) {
        int2 p = st2[(size_t)k * EE + base + i];
        int rl = p.x >> 17;
        int pos = atomicAdd(&cur[rl], 1);
        if (pos < BCAP) obuf[pos] = make_int2(p.x & 0x1FFFF, p.y);
    }
    __syncthreads();
    for (int i = tid; i < n; i += 1024)
        epair4[(size_t)k * EE + base + i] = obuf[i];
}

// ---- FUSED SpMM + MFMA split-bf16 dual-GEMM + GRU --------------------------
// 512 thr = 8 waves; block owns 64 rows. SpMM (relu(A.x), split-bf16) is
// computed in-kernel directly into the LDS slabs (no Rh/Rl globals, no
// gather kernel, no 51.2MB round-trip). Then phase A kb 0-11, re-stage Hpk,
// phase B kb 12-23 (kq-major, hi-weight dedup -> L1). setprio around MFMA.
template <bool FIRST, bool LAST>
__global__ __launch_bounds__(512, 4)
void gemm_gru_kernel(const float* __restrict__ x,
                     const int* __restrict__ row_ptr,
                     const int2* __restrict__ epair,
                     unsigned int* __restrict__ Hpk,
                     float* __restrict__ hout,
                     const unsigned short* __restrict__ Wp,
                     const float* __restrict__ bx,
                     const float* __restrict__ bh) {
    __shared__ unsigned short sA[2 * 64 * 128];   // 32 KB (hi, lo slabs)

    const int tid = threadIdx.x;
    const int row0 = blockIdx.x * 64;
    const int lane = tid & 63;
    const int w = tid >> 6;        // 0..7
    const int g = lane >> 4;       // 0..3
    const int m16 = lane & 15;

    // ---- fused SpMM: 16 half-waves x 4 passes; 32 lanes/row, float4/lane
    {
        const int hw = tid >> 5;       // 0..15
        const int l32 = tid & 31;
        const int d0 = l32 * 4;
        #pragma unroll
        for (int p = 0; p < 4; ++p) {
            int rl = p * 16 + hw;
            int grow = row0 + rl;
            float4 a0 = make_float4(0.f, 0.f, 0.f, 0.f);
            float4 a1 = a0, a2 = a0, a3 = a0;
            if (grow < NN) {
                int start = row_ptr[grow];
                int end = row_ptr[grow + 1];
                int e = start;
                for (; e + 3 < end; e += 4) {
                    int2 p0 = epair[e], p1 = epair[e + 1], p2 = epair[e + 2], p3 = epair[e + 3];
                    float4 x0 = *reinterpret_cast<const float4*>(x + (size_t)p0.x * DD + d0);
                    float4 x1 = *reinterpret_cast<const float4*>(x + (size_t)p1.x * DD + d0);
                    float4 x2 = *reinterpret_cast<const float4*>(x + (size_t)p2.x * DD + d0);
                    float4 x3 = *reinterpret_cast<const float4*>(x + (size_t)p3.x * DD + d0);
                    float v0 = __int_as_float(p0.y), v1 = __int_as_float(p1.y);
                    float v2 = __int_as_float(p2.y), v3 = __int_as_float(p3.y);
                    a0.x += v0 * x0.x; a0.y += v0 * x0.y; a0.z += v0 * x0.z; a0.w += v0 * x0.w;
                    a1.x += v1 * x1.x; a1.y += v1 * x1.y; a1.z += v1 * x1.z; a1.w += v1 * x1.w;
                    a2.x += v2 * x2.x; a2.y += v2 * x2.y; a2.z += v2 * x2.z; a2.w += v2 * x2.w;
                    a3.x += v3 * x3.x; a3.y += v3 * x3.y; a3.z += v3 * x3.z; a3.w += v3 * x3.w;
                }
                for (; e < end; ++e) {
                    int2 p0 = epair[e];
                    float v0 = __int_as_float(p0.y);
                    float4 x0 = *reinterpret_cast<const float4*>(x + (size_t)p0.x * DD + d0);
                    a0.x += v0 * x0.x; a0.y += v0 * x0.y; a0.z += v0 * x0.z; a0.w += v0 * x0.w;
                }
            }
            float o[4];
            o[0] = fmaxf((a0.x + a1.x) + (a2.x + a3.x), 0.f);
            o[1] = fmaxf((a0.y + a1.y) + (a2.y + a3.y), 0.f);
            o[2] = fmaxf((a0.z + a1.z) + (a2.z + a3.z), 0.f);
            o[3] = fmaxf((a0.w + a1.w) + (a2.w + a3.w), 0.f);
            ushort4 vh, vl;
            unsigned short h0 = bf16_rn(o[0]); vh.x = h0; vl.x = bf16_rn(o[0] - bf16_tf(h0));
            unsigned short h1 = bf16_rn(o[1]); vh.y = h1; vl.y = bf16_rn(o[1] - bf16_tf(h1));
            unsigned short h2 = bf16_rn(o[2]); vh.z = h2; vl.z = bf16_rn(o[2] - bf16_tf(h2));
            unsigned short h3 = bf16_rn(o[3]); vh.w = h3; vl.w = bf16_rn(o[3] - bf16_tf(h3));
            int slot = l32 >> 1;                       // d0/8
            int sw = slot ^ (rl & 7);
            int bi = ((0 * 64 + rl) * 16 + sw) * 8 + (d0 & 7);
            *reinterpret_cast<ushort4*>(sA + bi) = vh;
            *reinterpret_cast<ushort4*>(sA + (64 * 128) + bi) = vl;
        }
    }
    __syncthreads();

    f32x4 acc[4][4];               // [gate][mt]
    #pragma unroll
    for (int G = 0; G < 4; ++G)
        #pragma unroll
        for (int mt = 0; mt < 4; ++mt)
            acc[G][mt] = (f32x4){0.f, 0.f, 0.f, 0.f};

    // stage B: packed Hpk -> de-interleave into hi/lo slabs
    auto stageH = [&]() {
        #pragma unroll
        for (int it = 0; it < 4; ++it) {
            int idx = it * 512 + tid;         // 0..2047
            int row = idx >> 5;               // 0..63
            int j0 = (idx & 31) * 4;
            int grow = row0 + row;
            uint4 v = make_uint4(0, 0, 0, 0);
            if (grow < NN)
                v = *reinterpret_cast<const uint4*>(Hpk + (size_t)grow * 128 + j0);
            ushort4 hh = make_ushort4(v.x & 0xFFFF, v.y & 0xFFFF, v.z & 0xFFFF, v.w & 0xFFFF);
            ushort4 hl = make_ushort4(v.x >> 16, v.y >> 16, v.z >> 16, v.w >> 16);
            int sw = (j0 >> 3) ^ (row & 7);
            int b0 = ((0 * 64 + row) * 16 + sw) * 8 + (j0 & 7);
            int b1 = ((1 * 64 + row) * 16 + sw) * 8 + (j0 & 7);
            *reinterpret_cast<ushort4*>(sA + b0) = hh;
            *reinterpret_cast<ushort4*>(sA + b1) = hl;
        }
    };

    // one 12-MFMA cluster: B from panel kbW, A from slab arr at k-quad kq
    auto do_kb2 = [&](int kbW, int kq, int arr, int G0, int G1, int G2) {
        bf16x8 bfr[3];
        const int Gs[3] = {G0, G1, G2};
        #pragma unroll
        for (int i = 0; i < 3; ++i) {
            int n = Gs[i] * 128 + w * 16 + m16;
            bfr[i] = *reinterpret_cast<const bf16x8*>(
                Wp + ((size_t)(kbW * 512 + n)) * 32 + g * 8);
        }
        bf16x8 afr[4];
        #pragma unroll
        for (int mt = 0; mt < 4; ++mt) {
            int row = mt * 16 + m16;
            int sw = (kq * 4 + g) ^ (row & 7);
            afr[mt] = *reinterpret_cast<const bf16x8*>(
                sA + ((arr * 64 + row) * 16 + sw) * 8);
        }
        __builtin_amdgcn_s_setprio(1);
        #pragma unroll
        for (int mt = 0; mt < 4; ++mt) {
            acc[G0][mt] = __builtin_amdgcn_mfma_f32_16x16x32_bf16(afr[mt], bfr[0], acc[G0][mt], 0, 0, 0);
            acc[G1][mt] = __builtin_amdgcn_mfma_f32_16x16x32_bf16(afr[mt], bfr[1], acc[G1][mt], 0, 0, 0);
            acc[G2][mt] = __builtin_amdgcn_mfma_f32_16x16x32_bf16(afr[mt], bfr[2], acc[G2][mt], 0, 0, 0);
        }
        __builtin_amdgcn_s_setprio(0);
    };

    // phase A: x-side, kq-major; Whi panel reused (2nd use hits L1)
    for (int kq = 0; kq < 4; ++kq) {
        do_kb2(kq,     kq, 0, 0, 1, 2);   // Rh x Whi
        do_kb2(kq,     kq, 1, 0, 1, 2);   // Rl x Whi (L1 hit)
        do_kb2(8 + kq, kq, 0, 0, 1, 2);   // Rh x Wlo
    }

    // phase B: h-side
    if (!FIRST) {
        __syncthreads();
        stageH();
        __syncthreads();
        for (int kq = 0; kq < 4; ++kq) {
            do_kb2(12 + kq, kq, 0, 0, 1, 3);   // Hh x Whi_h
            do_kb2(12 + kq, kq, 1, 0, 1, 3);   // Hl x Whi_h (L1 hit)
            do_kb2(20 + kq, kq, 0, 0, 1, 3);   // Hh x Wlo_h
        }
    }

    // ---- GRU epilogue: C layout col=m16, row=g*4+ii (m89)
    {
        int j = w * 16 + m16;
        float bxr = bx[j], bxi = bx[128 + j], bxn = bx[256 + j];
        float bhr = bh[j], bhi = bh[128 + j], bhn = bh[256 + j];
        #pragma unroll
        for (int mt = 0; mt < 4; ++mt) {
            #pragma unroll
            for (int ii = 0; ii < 4; ++ii) {
                int lrow = mt * 16 + g * 4 + ii;
                int grow = row0 + lrow;
                if (grow >= NN) continue;
                float rr = acc[0][mt][ii] + bxr + bhr;
                float ri = acc[1][mt][ii] + bxi + bhi;
                float rin = acc[2][mt][ii] + bxn;
                float rhn = bhn;
                float ho = 0.f;
                if (!FIRST) {
                    rhn += acc[3][mt][ii];
                    int sw = (j >> 3) ^ (lrow & 7);
                    int bi = (lrow * 16 + sw) * 8 + (j & 7);
                    ho = bf16_tf(sA[bi]) + bf16_tf(sA[64 * 128 + bi]);
                }
                float rg = sigmoid_f(rr);
                float ig = sigmoid_f(ri);
                float ng = tanh_f(rin + rg * rhn);
                float hy = ng + ig * (ho - ng);
                if (LAST) {
                    hout[(size_t)grow * 128 + j] = hy;
                } else {
                    unsigned short hh = bf16_rn(hy);
                    unsigned short hl = bf16_rn(hy - bf16_tf(hh));
                    Hpk[(size_t)grow * 128 + j] = (unsigned)hh | ((unsigned)hl << 16);
                }
            }
        }
    }
}

// LayerNorm
__global__ __launch_bounds__(256) void ln_kernel(float* __restrict__ h,
                                                 const float* __restrict__ g,
                                                 const float* __restrict__ b) {
    int tid = threadIdx.x;
    int lane = tid & 31;
    int rl = tid >> 5;
    int row = blockIdx.x * 8 + rl;
    if (row >= NN) return;
    float4 v = *reinterpret_cast<const float4*>(h + (size_t)row * DD + lane * 4);
    float s = v.x + v.y + v.z + v.w;
    #pragma unroll
    for (int m = 16; m >= 1; m >>= 1) s += __shfl_xor(s, m, 64);
    float mean = s * (1.0f / DD);
    float dx = v.x - mean, dy = v.y - mean, dz = v.z - mean, dw = v.w - mean;
    float q = dx * dx + dy * dy + dz * dz + dw * dw;
    #pragma unroll
    for (int m = 16; m >= 1; m >>= 1) q += __shfl_xor(q, m, 64);
    float var = q * (1.0f / DD);
    float inv = 1.0f / sqrtf(var + 1e-5f);
    float4 gv = *reinterpret_cast<const float4*>(g + lane * 4);
    float4 bv = *reinterpret_cast<const float4*>(b + lane * 4);
    float4 o;
    o.x = dx * inv * gv.x + bv.x;
    o.y = dy * inv * gv.y + bv.y;
    o.z = dz * inv * gv.z + bv.z;
    o.w = dw * inv * gv.w + bv.w;
    *reinterpret_cast<float4*>(h + (size_t)row * DD + lane * 4) = o;
}

static inline size_t align_up(size_t v, size_t a) { return (v + a - 1) & ~(a - 1); }

extern "C" void kernel_launch(void* const* d_in, const int* in_sizes, int n_in,
                              void* d_out, int out_size, void* d_ws, size_t ws_size,
                              hipStream_t stream) {
    const float* x    = (const float*)d_in[0];
    const float* vals = (const float*)d_in[1];
    const float* wx   = (const float*)d_in[2];
    const float* bx   = (const float*)d_in[3];
    const float* wh   = (const float*)d_in[4];
    const float* bh   = (const float*)d_in[5];
    const float* lng  = (const float*)d_in[6];
    const float* lnb  = (const float*)d_in[7];
    const int* rows   = (const int*)d_in[8];
    const int* cols   = (const int*)d_in[9];

    float* hout = (float*)d_out;

    size_t off = 0;
    char* wsb = (char*)d_ws;
    int2* st2 = (int2*)(wsb + off);     off = align_up(off + (size_t)4 * EE * 8, 256);
    unsigned int* Hpk = (unsigned int*)(wsb + off);    off = align_up(off + (size_t)NN * DD * 4, 256);
    unsigned short* Wp = (unsigned short*)(wsb + off); off = align_up(off + (size_t)24 * 512 * 32 * 2, 256);
    int* row_ptr4 = (int*)(wsb + off);  off = align_up(off + (size_t)4 * (NN + 1) * 4, 256);
    int2* epair4 = (int2*)(wsb + off);  off = align_up(off + (size_t)4 * EE * 8, 256);
    int* bcnt4 = (int*)(wsb + off);     off = align_up(off + (size_t)4 * NBK * 4, 256);
    int* bbase4 = (int*)(wsb + off);    off = align_up(off + (size_t)4 * NBK * 4, 256);
    int* bcur4 = (int*)(wsb + off);     off = align_up(off + (size_t)4 * NBK * 4, 256);

    (void)in_sizes; (void)n_in; (void)out_size; (void)ws_size;

    pack_w_kernel<<<1536, 256, 0, stream>>>(wx, wh, Wp);

    hipMemsetAsync(bcnt4, 0, (size_t)4 * NBK * sizeof(int), stream);
    dim3 e2grid((EE + 2047) / 2048, 4);          // 293 x 4
    bhist_kernel<<<e2grid, 256, 0, stream>>>(rows, bcnt4);
    bscan_kernel<<<1, 64, 0, stream>>>(bcnt4, bbase4, bcur4);
    bscat_kernel<<<e2grid, 256, 0, stream>>>(rows, cols, vals, bcur4, st2);
    dim3 sgrid(NBK, 4);                          // 49 x 4
    sort2_kernel<<<sgrid, 1024, 0, stream>>>(st2, bbase4, bcnt4, row_ptr4, epair4);

    const int mgrid = (NN + 63) / 64;         // 782

    for (int s = 0; s < 4; ++s) {
        int k = 3 - s;  // adj_list reversed
        const int* rp = row_ptr4 + (size_t)k * (NN + 1);
        const int2* ep = epair4 + (size_t)k * EE;
        if (s == 0)
            gemm_gru_kernel<true, false><<<mgrid, 512, 0, stream>>>(
                x, rp, ep, Hpk, hout, Wp, bx, bh);
        else if (s < 3)
            gemm_gru_kernel<false, false><<<mgrid, 512, 0, stream>>>(
                x, rp, ep, Hpk, hout, Wp, bx, bh);
        else
            gemm_gru_kernel<false, true><<<mgrid, 512, 0, stream>>>(
                x, rp, ep, Hpk, hout, Wp, bx, bh);
    }

    ln_kernel<<<(NN + 7) / 8, 256, 0, stream>>>(hout, lng, lnb);
}